// Round 1
// baseline (26.256 us; speedup 1.0000x reference)
//
#include <hip/hip_runtime.h>
#include <math.h>

#define BN_EPS 1e-5f
#define BATCH  16
#define NCH    64
#define EEGL   256
#define LWIN   193   // EEGL - CTX + 1
#define NO     16    // F1*D = conv2 output channels = F2

// ---------------------------------------------------------------------------
// Kernel A: U[b][o][s] = sum_c w2[o][c] * eeg[b][c][s]   (b,o in [0,16), s in [0,256))
// plus (block 0,0) fold all BN/bias constants into cst[0..496]:
//   cst[  0+o]=A   cst[ 16+o]=B   cst[ 32+o]=C   cst[ 48+o]=K     (conv1+bn1+conv2+bn2 folded)
//   cst[ 64+o]=w3_0 cst[80+o]=w3_1 cst[96+o]=w3_2 cst[112+o]=b3
//   cst[128+o]=K4 (s3*b4 + o3)    cst[144 + f*16 + o] = s3[f]*w4[f][o]
//   cst[400+i]=lin_w[i] (96)      cst[496]=lin_b
// ---------------------------------------------------------------------------
__global__ __launch_bounds__(256) void eegnet_prep(
    const float* __restrict__ eeg, const float* __restrict__ w2,
    const float* __restrict__ c1w, const float* __restrict__ c1b,
    const float* __restrict__ bn1g, const float* __restrict__ bn1b,
    const float* __restrict__ bn1m, const float* __restrict__ bn1v,
    const float* __restrict__ c2b,
    const float* __restrict__ bn2g, const float* __restrict__ bn2b,
    const float* __restrict__ bn2m, const float* __restrict__ bn2v,
    const float* __restrict__ c3w, const float* __restrict__ c3b,
    const float* __restrict__ c4w, const float* __restrict__ c4b,
    const float* __restrict__ bn3g, const float* __restrict__ bn3b,
    const float* __restrict__ bn3m, const float* __restrict__ bn3v,
    const float* __restrict__ linw, const float* __restrict__ linb,
    float* __restrict__ U, float* __restrict__ cst)
{
    const int b = blockIdx.x;    // 16
    const int o = blockIdx.y;    // 16
    const int s = threadIdx.x;   // 256

    const float* ep = eeg + b * NCH * EEGL + s;
    const float* wp = w2 + o * NCH;          // uniform per block -> scalar loads
    float acc = 0.f;
    #pragma unroll
    for (int c = 0; c < NCH; ++c)
        acc = fmaf(wp[c], ep[c * EEGL], acc);
    U[(b * NO + o) * EEGL + s] = acc;

    if (b == 0 && o == 0) {
        const int t = threadIdx.x;
        if (t < NO) {
            const int oc = t, g = oc >> 1;
            const float s1 = bn1g[g] / sqrtf(bn1v[g] + BN_EPS);
            const float o1 = bn1b[g] - bn1m[g] * s1;
            const float s2 = bn2g[oc] / sqrtf(bn2v[oc] + BN_EPS);
            const float o2 = bn2b[oc] - bn2m[oc] * s2;
            float S2 = 0.f;
            for (int c = 0; c < NCH; ++c) S2 += w2[oc * NCH + c];
            const float ss = s2 * s1;
            cst[  0 + oc] = ss * c1w[g * 3 + 0];
            cst[ 16 + oc] = ss * c1w[g * 3 + 1];
            cst[ 32 + oc] = ss * c1w[g * 3 + 2];
            cst[ 48 + oc] = s2 * (fmaf(s1, c1b[g], o1) * S2 + c2b[oc]) + o2;
            cst[ 64 + oc] = c3w[oc * 3 + 0];
            cst[ 80 + oc] = c3w[oc * 3 + 1];
            cst[ 96 + oc] = c3w[oc * 3 + 2];
            cst[112 + oc] = c3b[oc];
            const float s3 = bn3g[oc] / sqrtf(bn3v[oc] + BN_EPS);
            const float o3 = bn3b[oc] - bn3m[oc] * s3;
            cst[128 + oc] = fmaf(s3, c4b[oc], o3);
            for (int c = 0; c < NO; ++c)
                cst[144 + oc * NO + c] = s3 * c4w[oc * NO + c];
        }
        if (t < 96) cst[400 + t] = linw[t];
        if (t == 0) cst[496] = linb[0];
    }
}

// ---------------------------------------------------------------------------
// Kernel B: one 64-lane wave per window (b,l).
//   a[o][t] = elu(A*Uw[t-1] + B*Uw[t] + C*Uw[t+1] + K)   (window-local zero pad)
//   p[o][j] = avg pair; q[o][j] = depthwise 1x3 + b3; r[f][j] = 1x1 conv (s3-folded)
//   e = elu(r + K4); y = (1/5) * sum_{f, j<30} lw[f*6 + j/5] * e[f][j] + lb
// ---------------------------------------------------------------------------
__global__ __launch_bounds__(64) void eegnet_win(
    const float* __restrict__ U, const float* __restrict__ cst,
    float* __restrict__ out)
{
    const int win = blockIdx.x;          // 3088
    const int b = win / LWIN;
    const int l = win - b * LWIN;
    const int t = threadIdx.x;           // 64

    __shared__ float cs[512];
    __shared__ float Uw[NO][64];
    __shared__ float aS[NO][65];
    __shared__ float pS[NO][33];

    for (int i = t; i < 497; i += 64) cs[i] = cst[i];
    const float* Ub = U + b * NO * EEGL + l;
    #pragma unroll
    for (int o = 0; o < NO; ++o) Uw[o][t] = Ub[o * EEGL + t];
    __syncthreads();

    const float* CA  = cs;        const float* CB  = cs + 16;
    const float* CC  = cs + 32;   const float* CK  = cs + 48;
    const float* W30 = cs + 64;   const float* W31 = cs + 80;
    const float* W32 = cs + 96;   const float* C3B = cs + 112;
    const float* K4  = cs + 128;  const float* W4  = cs + 144;
    const float* LW  = cs + 400;

    // conv1+bn1+conv2+bn2+elu at window position t, all 16 channels
    #pragma unroll
    for (int o = 0; o < NO; ++o) {
        const float um = (t > 0)  ? Uw[o][t - 1] : 0.f;
        const float uc = Uw[o][t];
        const float up = (t < 63) ? Uw[o][t + 1] : 0.f;
        const float x = fmaf(CA[o], um, fmaf(CB[o], uc, fmaf(CC[o], up, CK[o])));
        aS[o][t] = x > 0.f ? x : expm1f(x);
    }
    __syncthreads();

    // avgpool k=2
    if (t < 32) {
        #pragma unroll
        for (int o = 0; o < NO; ++o)
            pS[o][t] = 0.5f * (aS[o][2 * t] + aS[o][2 * t + 1]);
    }
    __syncthreads();

    float partial = 0.f;
    if (t < 30) {   // positions j=30,31 are dropped by the k=5 VALID pool
        float q[NO];
        #pragma unroll
        for (int o = 0; o < NO; ++o) {
            const float pm = (t > 0)  ? pS[o][t - 1] : 0.f;
            const float pc = pS[o][t];
            const float pp = pS[o][t + 1];   // t<30 so t+1<=30 always valid
            q[o] = fmaf(W30[o], pm, fmaf(W31[o], pc, fmaf(W32[o], pp, C3B[o])));
        }
        const float* lwp = LW + (t / 5);     // lw[f*6 + t/5]
        #pragma unroll
        for (int f = 0; f < NO; ++f) {
            float r = K4[f];
            #pragma unroll
            for (int o = 0; o < NO; ++o)
                r = fmaf(W4[f * NO + o], q[o], r);
            const float e = r > 0.f ? r : expm1f(r);
            partial = fmaf(e, lwp[f * 6], partial);
        }
    }

    // wave reduction over 64 lanes (lanes >=30 hold 0)
    #pragma unroll
    for (int off = 32; off > 0; off >>= 1)
        partial += __shfl_down(partial, off, 64);
    if (t == 0)
        out[win] = fmaf(partial, 0.2f, cs[496]);
}

extern "C" void kernel_launch(void* const* d_in, const int* in_sizes, int n_in,
                              void* d_out, int out_size, void* d_ws, size_t ws_size,
                              hipStream_t stream) {
    const float* eeg  = (const float*)d_in[0];
    // d_in[1] = env, unused by the reference computation
    const float* c1w  = (const float*)d_in[2];
    const float* c1b  = (const float*)d_in[3];
    const float* bn1g = (const float*)d_in[4];
    const float* bn1b = (const float*)d_in[5];
    const float* bn1m = (const float*)d_in[6];
    const float* bn1v = (const float*)d_in[7];
    const float* w2   = (const float*)d_in[8];
    const float* c2b  = (const float*)d_in[9];
    const float* bn2g = (const float*)d_in[10];
    const float* bn2b = (const float*)d_in[11];
    const float* bn2m = (const float*)d_in[12];
    const float* bn2v = (const float*)d_in[13];
    const float* c3w  = (const float*)d_in[14];
    const float* c3b  = (const float*)d_in[15];
    const float* c4w  = (const float*)d_in[16];
    const float* c4b  = (const float*)d_in[17];
    const float* bn3g = (const float*)d_in[18];
    const float* bn3b = (const float*)d_in[19];
    const float* bn3m = (const float*)d_in[20];
    const float* bn3v = (const float*)d_in[21];
    const float* linw = (const float*)d_in[22];
    const float* linb = (const float*)d_in[23];

    float* U   = (float*)d_ws;                 // 16*16*256 f32 = 256 KB
    float* cst = U + BATCH * NO * EEGL;        // 497 f32

    eegnet_prep<<<dim3(BATCH, NO), 256, 0, stream>>>(
        eeg, w2, c1w, c1b, bn1g, bn1b, bn1m, bn1v, c2b,
        bn2g, bn2b, bn2m, bn2v, c3w, c3b, c4w, c4b,
        bn3g, bn3b, bn3m, bn3v, linw, linb, U, cst);

    eegnet_win<<<dim3(BATCH * LWIN), 64, 0, stream>>>(U, cst, (float*)d_out);
}

// Round 2
// 26.017 us; speedup vs baseline: 1.0092x; 1.0092x over previous
//
#include <hip/hip_runtime.h>
#include <math.h>

#define BN_EPS 1e-5f
#define LWIN   193          // 256 - 64 + 1

__device__ __forceinline__ float elu(float x) { return x > 0.f ? x : expm1f(x); }

// One block per batch element b. 1024 threads = 16 waves.
// Phases (all intermediates LDS-resident):
//   U[o][s]  = sum_c w2[o][c] * eeg[b][c][s]                (16x256)
//   E[o][s]  = elu(A*U[s-1]+B*U[s]+C*U[s+1]+K)              (window-interior conv1+bn1+conv2+bn2)
//   P2[o][s] = (E[s]+E[s+1])/2                              (interior pool1)
//   Q[o][s]  = w30*P2[s-2]+w31*P2[s]+w32*P2[s+2]+b3         (interior depthwise-3)
//   Ef[f][s] = elu(sum_o W4f[f][o]*Q[o][s] + K4[f])         (1x1 conv + bn3 + elu)
//   S5[f][s] = Ef[s]+Ef[s+2]+Ef[s+4]+Ef[s+6]+Ef[s+8]        (pool5 group sums)
//   y(l) = lb + 0.2*[ sum_{f,g} lw[f,g]*S5[f][l+10g]
//                     + sum_f lw[f,0]*(e_q0+e_q1 - Ef[f][l] - Ef[f][l+2]) ]
// where e_q0/e_q1 are the true j=0,1 values built from the window-edge p[0].
__global__ __launch_bounds__(1024) void eegnet_fused(
    const float* __restrict__ eeg,
    const float* __restrict__ c1w, const float* __restrict__ c1b,
    const float* __restrict__ bn1g, const float* __restrict__ bn1b,
    const float* __restrict__ bn1m, const float* __restrict__ bn1v,
    const float* __restrict__ w2,  const float* __restrict__ c2b,
    const float* __restrict__ bn2g, const float* __restrict__ bn2b,
    const float* __restrict__ bn2m, const float* __restrict__ bn2v,
    const float* __restrict__ c3w, const float* __restrict__ c3b,
    const float* __restrict__ c4w, const float* __restrict__ c4b,
    const float* __restrict__ bn3g, const float* __restrict__ bn3b,
    const float* __restrict__ bn3m, const float* __restrict__ bn3v,
    const float* __restrict__ linw, const float* __restrict__ linb,
    float* __restrict__ out)
{
    const int b   = blockIdx.x;
    const int tid = threadIdx.x;
    const int s   = tid & 255;
    // tid>>8 is constant within each 64-aligned wave; force SGPR so w2 reads scalarize
    const int oqu = __builtin_amdgcn_readfirstlane(tid >> 8);   // 0..3

    __shared__ float Ul [16][256];
    __shared__ float El [16][256];
    __shared__ float P2 [16][256];
    __shared__ float Ql [16][256];
    __shared__ float Efs[16][256];
    __shared__ float S5 [16][256];
    __shared__ float cs[512];   // [0]A [16]B [32]C [48]K [64]w30 [80]w31 [96]w32 [112]b3
                                // [128]K4 [144]W4f[f*16+o] [400]lw[96] [496]lb
    __shared__ float S2s[16];

    // --- S2[oc] = sum_c w2[oc][c]  (needed for the K fold) ---
    if (tid < 256) {
        const int oc = tid >> 4, ln = tid & 15;
        const float* wr = w2 + oc * 64 + ln;
        float p = wr[0] + wr[16] + wr[32] + wr[48];
        p += __shfl_xor(p, 1);
        p += __shfl_xor(p, 2);
        p += __shfl_xor(p, 4);
        p += __shfl_xor(p, 8);
        if (ln == 0) S2s[oc] = p;
    }

    // --- U phase: thread (oq,s) computes 4 output channels ---
    {
        const float* ep = eeg + b * 64 * 256 + s;
        const float* wb = w2 + oqu * 4 * 64;       // wave-uniform -> s_loads
        float a0 = 0.f, a1 = 0.f, a2 = 0.f, a3 = 0.f;
        #pragma unroll 16
        for (int c = 0; c < 64; ++c) {
            const float e = ep[c * 256];
            a0 = fmaf(wb[c      ], e, a0);
            a1 = fmaf(wb[64  + c], e, a1);
            a2 = fmaf(wb[128 + c], e, a2);
            a3 = fmaf(wb[192 + c], e, a3);
        }
        Ul[oqu*4+0][s] = a0;  Ul[oqu*4+1][s] = a1;
        Ul[oqu*4+2][s] = a2;  Ul[oqu*4+3][s] = a3;
    }
    __syncthreads();

    // --- fold constants ---
    if (tid < 16) {
        const int f = tid, g = f >> 1;
        const float s1 = bn1g[g] / sqrtf(bn1v[g] + BN_EPS);
        const float o1 = bn1b[g] - bn1m[g] * s1;
        const float s2 = bn2g[f] / sqrtf(bn2v[f] + BN_EPS);
        const float o2 = bn2b[f] - bn2m[f] * s2;
        const float ss = s2 * s1;
        cs[      f] = ss * c1w[g*3+0];
        cs[ 16 + f] = ss * c1w[g*3+1];
        cs[ 32 + f] = ss * c1w[g*3+2];
        cs[ 48 + f] = s2 * (fmaf(s1, c1b[g], o1) * S2s[f] + c2b[f]) + o2;
        cs[ 64 + f] = c3w[f*3+0];
        cs[ 80 + f] = c3w[f*3+1];
        cs[ 96 + f] = c3w[f*3+2];
        cs[112 + f] = c3b[f];
        const float s3 = bn3g[f] / sqrtf(bn3v[f] + BN_EPS);
        const float o3 = bn3b[f] - bn3m[f] * s3;
        cs[128 + f] = fmaf(s3, c4b[f], o3);
        #pragma unroll
        for (int o = 0; o < 16; ++o)
            cs[144 + f*16 + o] = s3 * c4w[f*16 + o];
    }
    if (tid >= 64 && tid < 160) cs[400 + tid - 64] = linw[tid - 64];
    if (tid == 160)             cs[496] = linb[0];
    __syncthreads();

    // --- E phase ---
    #pragma unroll
    for (int i = 0; i < 4; ++i) {
        const int o = oqu*4 + i;
        const float um = (s >= 1)   ? Ul[o][s-1] : 0.f;
        const float uc = Ul[o][s];
        const float up = (s <= 254) ? Ul[o][s+1] : 0.f;
        El[o][s] = elu(fmaf(cs[o], um, fmaf(cs[16+o], uc, fmaf(cs[32+o], up, cs[48+o]))));
    }
    __syncthreads();

    // --- P2 phase ---
    {
        const int sp1 = (s <= 254) ? s + 1 : 255;
        #pragma unroll
        for (int i = 0; i < 4; ++i) {
            const int o = oqu*4 + i;
            P2[o][s] = 0.5f * (El[o][s] + El[o][sp1]);
        }
    }
    __syncthreads();

    // --- Q phase ---
    {
        const int sm2 = (s >= 2)   ? s - 2 : 0;
        const int sp2 = (s <= 253) ? s + 2 : 255;
        #pragma unroll
        for (int i = 0; i < 4; ++i) {
            const int o = oqu*4 + i;
            Ql[o][s] = fmaf(cs[64+o], P2[o][sm2],
                       fmaf(cs[80+o], P2[o][s],
                       fmaf(cs[96+o], P2[o][sp2], cs[112+o])));
        }
    }
    __syncthreads();

    // --- R / Ef phase ---
    {
        float q[16];
        #pragma unroll
        for (int o = 0; o < 16; ++o) q[o] = Ql[o][s];
        #pragma unroll
        for (int i = 0; i < 4; ++i) {
            const int f = oqu*4 + i;
            float r = cs[128 + f];
            #pragma unroll
            for (int o = 0; o < 16; ++o)
                r = fmaf(cs[144 + f*16 + o], q[o], r);
            Efs[f][s] = elu(r);
        }
    }
    __syncthreads();

    // --- S5 phase ---
    {
        const int i2 = (s <= 253) ? s+2 : 255, i4 = (s <= 251) ? s+4 : 255;
        const int i6 = (s <= 249) ? s+6 : 255, i8 = (s <= 247) ? s+8 : 255;
        #pragma unroll
        for (int i = 0; i < 4; ++i) {
            const int f = oqu*4 + i;
            S5[f][s] = Efs[f][s] + Efs[f][i2] + Efs[f][i4] + Efs[f][i6] + Efs[f][i8];
        }
    }
    __syncthreads();

    // --- Y phase: thread (l, fq); 4 lanes per window ---
    if (tid < LWIN * 4) {
        const int l = tid >> 2, fq = tid & 3;
        float q0[16], q1[16];
        #pragma unroll
        for (int o = 0; o < 16; ++o) {
            // window-edge t=0: conv1 left tap padded away
            const float z0 = fmaf(cs[16+o], Ul[o][l], fmaf(cs[32+o], Ul[o][l+1], cs[48+o]));
            const float P0 = 0.5f * (elu(z0) + El[o][l+1]);
            const float pa = P2[o][l+2], pb = P2[o][l+4];
            q0[o] = fmaf(cs[80+o], P0, fmaf(cs[96+o], pa, cs[112+o]));                    // j=0 (left pad)
            q1[o] = fmaf(cs[64+o], P0, fmaf(cs[80+o], pa, fmaf(cs[96+o], pb, cs[112+o]))); // j=1
        }
        float part = 0.f;
        #pragma unroll
        for (int i = 0; i < 4; ++i) {
            const int f = fq*4 + i;
            float r0 = cs[128+f], r1 = cs[128+f];
            #pragma unroll
            for (int o = 0; o < 16; ++o) {
                const float w = cs[144 + f*16 + o];
                r0 = fmaf(w, q0[o], r0);
                r1 = fmaf(w, q1[o], r1);
            }
            const float corr = elu(r0) + elu(r1) - Efs[f][l] - Efs[f][l+2];
            part = fmaf(cs[400 + f*6], corr, part);
            #pragma unroll
            for (int g = 0; g < 6; ++g)
                part = fmaf(cs[400 + f*6 + g], S5[f][l + 10*g], part);
        }
        part += __shfl_xor(part, 1);
        part += __shfl_xor(part, 2);
        if (fq == 0) out[b * LWIN + l] = fmaf(0.2f, part, cs[496]);
    }
}

extern "C" void kernel_launch(void* const* d_in, const int* in_sizes, int n_in,
                              void* d_out, int out_size, void* d_ws, size_t ws_size,
                              hipStream_t stream) {
    const float* eeg  = (const float*)d_in[0];
    // d_in[1] = env, unused by the reference computation
    const float* c1w  = (const float*)d_in[2];
    const float* c1b  = (const float*)d_in[3];
    const float* bn1g = (const float*)d_in[4];
    const float* bn1b = (const float*)d_in[5];
    const float* bn1m = (const float*)d_in[6];
    const float* bn1v = (const float*)d_in[7];
    const float* w2   = (const float*)d_in[8];
    const float* c2b  = (const float*)d_in[9];
    const float* bn2g = (const float*)d_in[10];
    const float* bn2b = (const float*)d_in[11];
    const float* bn2m = (const float*)d_in[12];
    const float* bn2v = (const float*)d_in[13];
    const float* c3w  = (const float*)d_in[14];
    const float* c3b  = (const float*)d_in[15];
    const float* c4w  = (const float*)d_in[16];
    const float* c4b  = (const float*)d_in[17];
    const float* bn3g = (const float*)d_in[18];
    const float* bn3b = (const float*)d_in[19];
    const float* bn3m = (const float*)d_in[20];
    const float* bn3v = (const float*)d_in[21];
    const float* linw = (const float*)d_in[22];
    const float* linb = (const float*)d_in[23];

    eegnet_fused<<<16, 1024, 0, stream>>>(
        eeg, c1w, c1b, bn1g, bn1b, bn1m, bn1v, w2, c2b,
        bn2g, bn2b, bn2m, bn2v, c3w, c3b, c4w, c4b,
        bn3g, bn3b, bn3m, bn3v, linw, linb, (float*)d_out);
}

// Round 3
// 18.146 us; speedup vs baseline: 1.4469x; 1.4337x over previous
//
#include <hip/hip_runtime.h>
#include <math.h>

#define BN_EPS 1e-5f
#define LWIN   193     // 256 - 64 + 1 windows
#define WPB    16      // windows per block
#define NBL    13      // ceil(193/16)
#define SLOC   96      // local sequence positions per block (needs 79 real + halo)
#define STR    97      // LDS row stride (96 % 32 == 0 would alias banks)

__device__ __forceinline__ float elu(float x) { return x > 0.f ? x : expm1f(x); }

// Grid: (16 batch, 13 window-chunks), 256 threads (4 waves).
// Block (b, wb) handles windows l in [L0, L0+16), L0 = 16*wb.
// Local coordinate i maps to global sequence position s = g0 + i, g0 = L0-3.
// All per-channel intermediates are 16 x 96 LDS arrays; everything outside the
// real range is clamped-junk that is finite and only feeds exactly-cancelling
// terms (same algebra as the validated round-2 kernel, absmax 0.0).
__global__ __launch_bounds__(256) void eegnet_fused(
    const float* __restrict__ eeg,
    const float* __restrict__ c1w, const float* __restrict__ c1b,
    const float* __restrict__ bn1g, const float* __restrict__ bn1b,
    const float* __restrict__ bn1m, const float* __restrict__ bn1v,
    const float* __restrict__ w2,  const float* __restrict__ c2b,
    const float* __restrict__ bn2g, const float* __restrict__ bn2b,
    const float* __restrict__ bn2m, const float* __restrict__ bn2v,
    const float* __restrict__ c3w, const float* __restrict__ c3b,
    const float* __restrict__ c4w, const float* __restrict__ c4b,
    const float* __restrict__ bn3g, const float* __restrict__ bn3b,
    const float* __restrict__ bn3m, const float* __restrict__ bn3v,
    const float* __restrict__ linw, const float* __restrict__ linb,
    float* __restrict__ out)
{
    const int b   = blockIdx.x;
    const int L0  = blockIdx.y * WPB;
    const int g0  = L0 - 3;
    const int tid = threadIdx.x;
    const int lane16 = tid & 15;    // channel index in phases
    const int grp16  = tid >> 4;    // position base in phases

    __shared__ float Eg[64][SLOC];          // eeg slice
    __shared__ float Ul[16][STR];           // U = depthwise-spatial collapse
    __shared__ float El[16][STR];           // elu(conv1+bn1+conv2+bn2), interior
    __shared__ float P2[16][STR];           // pool-2, interior
    __shared__ float Ql[16][STR];           // depthwise-3, interior
    __shared__ float Ef[16][STR];           // elu(1x1 + bn3), interior
    __shared__ float S5[16][STR];           // pool-5 group sums
    __shared__ float w2t[64 * 16];          // w2 transposed [c][o]
    __shared__ float cs[512];               // folded constants
    __shared__ float q0s[16][17], q1s[16][17];

    // ---- stage eeg slice (clamped to [0,255]) and transposed w2 ----
    {
        const int wv = tid >> 6, ln = tid & 63;
        const float* ebase = eeg + b * 64 * 256;
        for (int c = wv; c < 64; c += 4) {
            int s1 = g0 + ln;       s1 = s1 < 0 ? 0 : (s1 > 255 ? 255 : s1);
            Eg[c][ln] = ebase[c * 256 + s1];
            if (ln < SLOC - 64) {
                int s2 = g0 + 64 + ln; s2 = s2 < 0 ? 0 : (s2 > 255 ? 255 : s2);
                Eg[c][64 + ln] = ebase[c * 256 + s2];
            }
        }
        for (int idx = tid; idx < 1024; idx += 256) {
            const int c = idx >> 4, o = idx & 15;
            w2t[idx] = w2[o * 64 + c];
        }
    }

    // ---- fold BN/bias constants ----
    // cs[0]A cs[16]B cs[32]C cs[48]K | cs[64]w30 cs[80]w31 cs[96]w32 cs[112]b3
    // cs[128]K4 | cs[144 + o*16 + f] = s3[f]*w4[f][o] (transposed) | cs[400]lw[96] cs[496]lb
    if (tid < 16) {
        const int f = tid, g = f >> 1;
        const float s1 = bn1g[g] / sqrtf(bn1v[g] + BN_EPS);
        const float o1 = bn1b[g] - bn1m[g] * s1;
        const float s2 = bn2g[f] / sqrtf(bn2v[f] + BN_EPS);
        const float o2 = bn2b[f] - bn2m[f] * s2;
        const float ss = s2 * s1;
        float S2 = 0.f;
        for (int c = 0; c < 64; ++c) S2 += w2[f * 64 + c];
        cs[      f] = ss * c1w[g * 3 + 0];
        cs[ 16 + f] = ss * c1w[g * 3 + 1];
        cs[ 32 + f] = ss * c1w[g * 3 + 2];
        cs[ 48 + f] = s2 * (fmaf(s1, c1b[g], o1) * S2 + c2b[f]) + o2;
        cs[ 64 + f] = c3w[f * 3 + 0];
        cs[ 80 + f] = c3w[f * 3 + 1];
        cs[ 96 + f] = c3w[f * 3 + 2];
        cs[112 + f] = c3b[f];
        const float s3 = bn3g[f] / sqrtf(bn3v[f] + BN_EPS);
        const float o3 = bn3b[f] - bn3m[f] * s3;
        cs[128 + f] = fmaf(s3, c4b[f], o3);
        #pragma unroll
        for (int o = 0; o < 16; ++o)
            cs[144 + o * 16 + f] = s3 * c4w[f * 16 + o];
    }
    if (tid >= 64 && tid < 160) cs[400 + tid - 64] = linw[tid - 64];
    if (tid == 160)             cs[496] = linb[0];
    __syncthreads();

    // ---- U phase: Ul[o][i] = sum_c w2[o][c] * eeg[c][g0+i] ----
    {
        float acc[6] = {0.f, 0.f, 0.f, 0.f, 0.f, 0.f};
        for (int c = 0; c < 64; ++c) {
            const float w = w2t[c * 16 + lane16];
            #pragma unroll
            for (int k = 0; k < 6; ++k)
                acc[k] = fmaf(w, Eg[c][grp16 + 16 * k], acc[k]);
        }
        #pragma unroll
        for (int k = 0; k < 6; ++k)
            Ul[lane16][grp16 + 16 * k] = acc[k];
    }
    __syncthreads();

    // ---- E phase (global zero-pad at s=0 / s=255) ----
    #pragma unroll
    for (int k = 0; k < 6; ++k) {
        const int i = grp16 + 16 * k, sg = g0 + i, o = lane16;
        const float um = (sg >= 1)   ? Ul[o][i > 0 ? i - 1 : 0] : 0.f;
        const float uc = Ul[o][i];
        const float up = (sg <= 254) ? Ul[o][i < SLOC - 1 ? i + 1 : SLOC - 1] : 0.f;
        El[o][i] = elu(fmaf(cs[o], um, fmaf(cs[16 + o], uc, fmaf(cs[32 + o], up, cs[48 + o]))));
    }
    __syncthreads();

    // ---- P2 phase ----
    #pragma unroll
    for (int k = 0; k < 6; ++k) {
        const int i = grp16 + 16 * k, o = lane16;
        const int ip = i < SLOC - 1 ? i + 1 : SLOC - 1;
        P2[o][i] = 0.5f * (El[o][i] + El[o][ip]);
    }
    __syncthreads();

    // ---- Q phase ----
    #pragma unroll
    for (int k = 0; k < 6; ++k) {
        const int i = grp16 + 16 * k, o = lane16;
        const int im = i >= 2 ? i - 2 : 0;
        const int ip = i < SLOC - 2 ? i + 2 : SLOC - 1;
        Ql[o][i] = fmaf(cs[64 + o], P2[o][im],
                   fmaf(cs[80 + o], P2[o][i],
                   fmaf(cs[96 + o], P2[o][ip], cs[112 + o])));
    }
    __syncthreads();

    // ---- Ef phase: 1x1 conv + bn3 + elu ----
    #pragma unroll
    for (int k = 0; k < 6; ++k) {
        const int i = grp16 + 16 * k, f = lane16;
        float r = cs[128 + f];
        #pragma unroll
        for (int o = 0; o < 16; ++o)
            r = fmaf(cs[144 + o * 16 + f], Ql[o][i], r);
        Ef[f][i] = elu(r);
    }
    __syncthreads();

    // ---- S5 phase ----
    #pragma unroll
    for (int k = 0; k < 6; ++k) {
        const int i = grp16 + 16 * k, f = lane16;
        const int i2 = i + 2 < SLOC ? i + 2 : SLOC - 1;
        const int i4 = i + 4 < SLOC ? i + 4 : SLOC - 1;
        const int i6 = i + 6 < SLOC ? i + 6 : SLOC - 1;
        const int i8 = i + 8 < SLOC ? i + 8 : SLOC - 1;
        S5[f][i] = Ef[f][i] + Ef[f][i2] + Ef[f][i4] + Ef[f][i6] + Ef[f][i8];
    }
    __syncthreads();

    // ---- Y1: per-window edge-corrected q0/q1 (thread = (window, channel)) ----
    {
        const int w = grp16, o = lane16, l = L0 + w;
        if (l < LWIN) {
            const int li = w + 3;   // local index of global position l
            const float z0 = fmaf(cs[16 + o], Ul[o][li], fmaf(cs[32 + o], Ul[o][li + 1], cs[48 + o]));
            const float P0 = 0.5f * (elu(z0) + El[o][li + 1]);
            const float pa = P2[o][li + 2], pb = P2[o][li + 4];
            q0s[w][o] = fmaf(cs[80 + o], P0, fmaf(cs[96 + o], pa, cs[112 + o]));
            q1s[w][o] = fmaf(cs[64 + o], P0, fmaf(cs[80 + o], pa, fmaf(cs[96 + o], pb, cs[112 + o])));
        }
    }
    __syncthreads();

    // ---- Y2: per-window output (thread = (window, filter)), reduce over f ----
    {
        const int w = grp16, f = lane16, l = L0 + w;
        float part = 0.f;
        if (l < LWIN) {
            const int li = w + 3;
            float r0 = cs[128 + f], r1 = r0;
            #pragma unroll
            for (int o = 0; o < 16; ++o) {
                const float wt = cs[144 + o * 16 + f];
                r0 = fmaf(wt, q0s[w][o], r0);
                r1 = fmaf(wt, q1s[w][o], r1);
            }
            part = cs[400 + f * 6] * (elu(r0) + elu(r1) - Ef[f][li] - Ef[f][li + 2]);
            #pragma unroll
            for (int g = 0; g < 6; ++g)
                part = fmaf(cs[400 + f * 6 + g], S5[f][li + 10 * g], part);
        }
        part += __shfl_xor(part, 1);
        part += __shfl_xor(part, 2);
        part += __shfl_xor(part, 4);
        part += __shfl_xor(part, 8);
        if (f == 0 && l < LWIN) out[b * LWIN + l] = fmaf(0.2f, part, cs[496]);
    }
}

extern "C" void kernel_launch(void* const* d_in, const int* in_sizes, int n_in,
                              void* d_out, int out_size, void* d_ws, size_t ws_size,
                              hipStream_t stream) {
    const float* eeg  = (const float*)d_in[0];
    // d_in[1] = env, unused by the reference computation
    const float* c1w  = (const float*)d_in[2];
    const float* c1b  = (const float*)d_in[3];
    const float* bn1g = (const float*)d_in[4];
    const float* bn1b = (const float*)d_in[5];
    const float* bn1m = (const float*)d_in[6];
    const float* bn1v = (const float*)d_in[7];
    const float* w2   = (const float*)d_in[8];
    const float* c2b  = (const float*)d_in[9];
    const float* bn2g = (const float*)d_in[10];
    const float* bn2b = (const float*)d_in[11];
    const float* bn2m = (const float*)d_in[12];
    const float* bn2v = (const float*)d_in[13];
    const float* c3w  = (const float*)d_in[14];
    const float* c3b  = (const float*)d_in[15];
    const float* c4w  = (const float*)d_in[16];
    const float* c4b  = (const float*)d_in[17];
    const float* bn3g = (const float*)d_in[18];
    const float* bn3b = (const float*)d_in[19];
    const float* bn3m = (const float*)d_in[20];
    const float* bn3v = (const float*)d_in[21];
    const float* linw = (const float*)d_in[22];
    const float* linb = (const float*)d_in[23];

    eegnet_fused<<<dim3(16, NBL), 256, 0, stream>>>(
        eeg, c1w, c1b, bn1g, bn1b, bn1m, bn1v, w2, c2b,
        bn2g, bn2b, bn2m, bn2v, c3w, c3b, c4w, c4b,
        bn3g, bn3b, bn3m, bn3v, linw, linb, (float*)d_out);
}

// Round 5
// 15.496 us; speedup vs baseline: 1.6944x; 1.1710x over previous
//
#include <hip/hip_runtime.h>
#include <math.h>

#define BN_EPS 1e-5f
#define LWIN   193     // 256 - 64 + 1 windows
#define WPB    16      // windows per block
#define NBL    13      // ceil(193/16)
#define SLOC   96      // local sequence positions per block (79 real + halo)
#define STR    97      // LDS row stride for phase arrays

typedef __attribute__((address_space(1))) const unsigned int gl_u32;
typedef __attribute__((address_space(3))) unsigned int lds_u32;

__device__ __forceinline__ float elu(float x) { return x > 0.f ? x : expm1f(x); }

// Grid: (16 batch, 13 window-chunks), 256 threads (4 waves).
// Block (b, wb) handles windows l in [L0, L0+16), L0 = 16*wb.
// Local coordinate i maps to global sequence position s = g0 + i, g0 = L0-3.
// Staging: in-range 16B chunks via async global_load_lds; edge chunks fall
// back to per-ELEMENT clamped scalar loads + ds_write_b128 (r4's per-chunk
// clamp SHIFTED edge chunks, corrupting real positions -> absmax 9.8e-3).
// Clamp-junk only ever feeds exactly-cancelling or discarded terms (r3
// validated this algebra at absmax 0.0).
__global__ __launch_bounds__(256) void eegnet_fused(
    const float* __restrict__ eeg,
    const float* __restrict__ c1w, const float* __restrict__ c1b,
    const float* __restrict__ bn1g, const float* __restrict__ bn1b,
    const float* __restrict__ bn1m, const float* __restrict__ bn1v,
    const float* __restrict__ w2,  const float* __restrict__ c2b,
    const float* __restrict__ bn2g, const float* __restrict__ bn2b,
    const float* __restrict__ bn2m, const float* __restrict__ bn2v,
    const float* __restrict__ c3w, const float* __restrict__ c3b,
    const float* __restrict__ c4w, const float* __restrict__ c4b,
    const float* __restrict__ bn3g, const float* __restrict__ bn3b,
    const float* __restrict__ bn3m, const float* __restrict__ bn3v,
    const float* __restrict__ linw, const float* __restrict__ linb,
    float* __restrict__ out)
{
    const int b   = blockIdx.x;
    const int L0  = blockIdx.y * WPB;
    const int g0  = L0 - 3;
    const int tid = threadIdx.x;
    const int lane16 = tid & 15;
    const int grp16  = tid >> 4;

    __shared__ __align__(16) float Eg[64 * SLOC];  // eeg slice, linear stride 96
    __shared__ float4 w2t4[64 * 4];      // [c][og]: w2 transposed, 4 o per float4
    __shared__ float  Ul[16][STR];
    __shared__ float  El[16][STR];
    __shared__ float  P2[16][STR];
    __shared__ float  Ql[16][STR];
    __shared__ float  Ef[16][STR];
    __shared__ float  S5[16][STR];
    __shared__ float  cs[512];           // folded constants (layout as r3)
    __shared__ float  q0s[16][17], q1s[16][17];

    const float* ebase = eeg + b * 64 * 256;

    // ---- eeg -> LDS: async 16B chunks where fully in-range, else exact
    //      per-element clamped fallback (disjoint LDS slots, no race) ----
    {
        const int wv = tid >> 6, ln = tid & 63;
        #pragma unroll
        for (int j = 0; j < 6; ++j) {
            const int n    = wv * 6 + j;          // chunk-instr index 0..23
            const int fidx = n * 256 + ln * 4;    // dest float index (lane x 16B)
            const int c    = fidx / SLOC;         // SLOC % 4 == 0 -> chunks stay in-row
            const int i    = fidx - c * SLOC;
            const int s    = g0 + i;
            if (s >= 0 && s <= 252) {
                __builtin_amdgcn_global_load_lds((gl_u32*)(ebase + c * 256 + s),
                                                 (lds_u32*)&Eg[n * 256], 16, 0, 0);
            } else {
                const float* row = ebase + c * 256;
                const int e0 = s     < 0 ? 0 : (s     > 255 ? 255 : s);
                const int e1 = s + 1 < 0 ? 0 : (s + 1 > 255 ? 255 : s + 1);
                const int e2 = s + 2 < 0 ? 0 : (s + 2 > 255 ? 255 : s + 2);
                const int e3 = s + 3 < 0 ? 0 : (s + 3 > 255 ? 255 : s + 3);
                *reinterpret_cast<float4*>(&Eg[fidx]) =
                    make_float4(row[e0], row[e1], row[e2], row[e3]);
            }
        }
    }

    // ---- w2 -> LDS transposed ----
    {
        const int og = tid >> 6, c = tid & 63, o0 = og * 4;
        w2t4[c * 4 + og] = make_float4(w2[(o0    ) * 64 + c], w2[(o0 + 1) * 64 + c],
                                       w2[(o0 + 2) * 64 + c], w2[(o0 + 3) * 64 + c]);
    }

    // ---- fold constants, parallel across waves ----
    // cs[0]A cs[16]B cs[32]C cs[48]K | cs[64]w30 cs[80]w31 cs[96]w32 cs[112]b3
    // cs[128]K4 | cs[144+o*16+f]=s3[f]*w4[f][o] | cs[400]lw[96] cs[496]lb
    if (tid < 64) {
        const int f = tid & 15, q = tid >> 4;
        float s2p = 0.f;
        #pragma unroll
        for (int k = 0; k < 16; ++k) s2p += w2[f * 64 + q * 16 + k];
        s2p += __shfl_xor(s2p, 16);
        s2p += __shfl_xor(s2p, 32);
        if (tid < 16) {
            const int g = f >> 1;
            const float s1 = bn1g[g] / sqrtf(bn1v[g] + BN_EPS);
            const float o1 = bn1b[g] - bn1m[g] * s1;
            const float s2 = bn2g[f] / sqrtf(bn2v[f] + BN_EPS);
            const float o2 = bn2b[f] - bn2m[f] * s2;
            const float ss = s2 * s1;
            cs[      f] = ss * c1w[g * 3 + 0];
            cs[ 16 + f] = ss * c1w[g * 3 + 1];
            cs[ 32 + f] = ss * c1w[g * 3 + 2];
            cs[ 48 + f] = s2 * (fmaf(s1, c1b[g], o1) * s2p + c2b[f]) + o2;
            cs[ 64 + f] = c3w[f * 3 + 0];
            cs[ 80 + f] = c3w[f * 3 + 1];
            cs[ 96 + f] = c3w[f * 3 + 2];
            cs[112 + f] = c3b[f];
        }
    } else if (tid < 128) {
        const int j = tid - 64, f = j & 15, quad = j >> 4;
        const float s3 = bn3g[f] / sqrtf(bn3v[f] + BN_EPS);
        if (quad == 0)
            cs[128 + f] = fmaf(s3, c4b[f], bn3b[f] - bn3m[f] * s3);
        #pragma unroll
        for (int k = 0; k < 4; ++k) {
            const int o = quad * 4 + k;
            cs[144 + o * 16 + f] = s3 * c4w[f * 16 + o];
        }
    } else if (tid < 224) {
        cs[400 + tid - 128] = linw[tid - 128];
    } else if (tid == 224) {
        cs[496] = linb[0];
    }
    __syncthreads();   // drains vmcnt (DMA) + lgkm (ds_writes)

    // ---- U phase: wave og owns channels o = 4*og..4*og+3 ----
    {
        const int p  = tid & 63;         // position 0..63
        const int og = tid >> 6;         // wave index (uniform) -> w2t4 reads broadcast
        const bool two = (p < 32);       // lanes 0..31 also handle position p+64
        float a0 = 0.f, a1 = 0.f, a2 = 0.f, a3 = 0.f;
        float b0 = 0.f, b1 = 0.f, b2 = 0.f, b3 = 0.f;
        #pragma unroll 8
        for (int c = 0; c < 64; ++c) {
            const float4 w = w2t4[c * 4 + og];       // ds_read_b128, wave-uniform
            const float  e = Eg[c * SLOC + p];       // conflict-free (2-way max)
            a0 = fmaf(w.x, e, a0); a1 = fmaf(w.y, e, a1);
            a2 = fmaf(w.z, e, a2); a3 = fmaf(w.w, e, a3);
            if (two) {
                const float e2 = Eg[c * SLOC + p + 64];
                b0 = fmaf(w.x, e2, b0); b1 = fmaf(w.y, e2, b1);
                b2 = fmaf(w.z, e2, b2); b3 = fmaf(w.w, e2, b3);
            }
        }
        const int o0 = og * 4;
        Ul[o0    ][p] = a0; Ul[o0 + 1][p] = a1;
        Ul[o0 + 2][p] = a2; Ul[o0 + 3][p] = a3;
        if (two) {
            Ul[o0    ][p + 64] = b0; Ul[o0 + 1][p + 64] = b1;
            Ul[o0 + 2][p + 64] = b2; Ul[o0 + 3][p + 64] = b3;
        }
    }
    __syncthreads();

    // ---- E phase (global zero-pad at s=0 / s=255) ----
    #pragma unroll
    for (int k = 0; k < 6; ++k) {
        const int i = grp16 + 16 * k, sg = g0 + i, o = lane16;
        const float um = (sg >= 1)   ? Ul[o][i > 0 ? i - 1 : 0] : 0.f;
        const float uc = Ul[o][i];
        const float up = (sg <= 254) ? Ul[o][i < SLOC - 1 ? i + 1 : SLOC - 1] : 0.f;
        El[o][i] = elu(fmaf(cs[o], um, fmaf(cs[16 + o], uc, fmaf(cs[32 + o], up, cs[48 + o]))));
    }
    __syncthreads();

    // ---- P2 phase ----
    #pragma unroll
    for (int k = 0; k < 6; ++k) {
        const int i = grp16 + 16 * k, o = lane16;
        const int ip = i < SLOC - 1 ? i + 1 : SLOC - 1;
        P2[o][i] = 0.5f * (El[o][i] + El[o][ip]);
    }
    __syncthreads();

    // ---- Q phase ----
    #pragma unroll
    for (int k = 0; k < 6; ++k) {
        const int i = grp16 + 16 * k, o = lane16;
        const int im = i >= 2 ? i - 2 : 0;
        const int ip = i < SLOC - 2 ? i + 2 : SLOC - 1;
        Ql[o][i] = fmaf(cs[64 + o], P2[o][im],
                   fmaf(cs[80 + o], P2[o][i],
                   fmaf(cs[96 + o], P2[o][ip], cs[112 + o])));
    }
    __syncthreads();

    // ---- Ef phase: 1x1 conv + bn3 + elu ----
    #pragma unroll
    for (int k = 0; k < 6; ++k) {
        const int i = grp16 + 16 * k, f = lane16;
        float r = cs[128 + f];
        #pragma unroll
        for (int o = 0; o < 16; ++o)
            r = fmaf(cs[144 + o * 16 + f], Ql[o][i], r);
        Ef[f][i] = elu(r);
    }
    __syncthreads();

    // ---- S5 phase ----
    #pragma unroll
    for (int k = 0; k < 6; ++k) {
        const int i = grp16 + 16 * k, f = lane16;
        const int i2 = i + 2 < SLOC ? i + 2 : SLOC - 1;
        const int i4 = i + 4 < SLOC ? i + 4 : SLOC - 1;
        const int i6 = i + 6 < SLOC ? i + 6 : SLOC - 1;
        const int i8 = i + 8 < SLOC ? i + 8 : SLOC - 1;
        S5[f][i] = Ef[f][i] + Ef[f][i2] + Ef[f][i4] + Ef[f][i6] + Ef[f][i8];
    }
    __syncthreads();

    // ---- Y1: per-window edge-corrected q0/q1 ----
    {
        const int w = grp16, o = lane16, l = L0 + w;
        if (l < LWIN) {
            const int li = w + 3;
            const float z0 = fmaf(cs[16 + o], Ul[o][li], fmaf(cs[32 + o], Ul[o][li + 1], cs[48 + o]));
            const float P0 = 0.5f * (elu(z0) + El[o][li + 1]);
            const float pa = P2[o][li + 2], pb = P2[o][li + 4];
            q0s[w][o] = fmaf(cs[80 + o], P0, fmaf(cs[96 + o], pa, cs[112 + o]));
            q1s[w][o] = fmaf(cs[64 + o], P0, fmaf(cs[80 + o], pa, fmaf(cs[96 + o], pb, cs[112 + o])));
        }
    }
    __syncthreads();

    // ---- Y2: per-window output, reduce over f ----
    {
        const int w = grp16, f = lane16, l = L0 + w;
        float part = 0.f;
        if (l < LWIN) {
            const int li = w + 3;
            float r0 = cs[128 + f], r1 = r0;
            #pragma unroll
            for (int o = 0; o < 16; ++o) {
                const float wt = cs[144 + o * 16 + f];
                r0 = fmaf(wt, q0s[w][o], r0);
                r1 = fmaf(wt, q1s[w][o], r1);
            }
            part = cs[400 + f * 6] * (elu(r0) + elu(r1) - Ef[f][li] - Ef[f][li + 2]);
            #pragma unroll
            for (int g = 0; g < 6; ++g)
                part = fmaf(cs[400 + f * 6 + g], S5[f][li + 10 * g], part);
        }
        part += __shfl_xor(part, 1);
        part += __shfl_xor(part, 2);
        part += __shfl_xor(part, 4);
        part += __shfl_xor(part, 8);
        if (f == 0 && l < LWIN) out[b * LWIN + l] = fmaf(0.2f, part, cs[496]);
    }
}

extern "C" void kernel_launch(void* const* d_in, const int* in_sizes, int n_in,
                              void* d_out, int out_size, void* d_ws, size_t ws_size,
                              hipStream_t stream) {
    const float* eeg  = (const float*)d_in[0];
    // d_in[1] = env, unused by the reference computation
    const float* c1w  = (const float*)d_in[2];
    const float* c1b  = (const float*)d_in[3];
    const float* bn1g = (const float*)d_in[4];
    const float* bn1b = (const float*)d_in[5];
    const float* bn1m = (const float*)d_in[6];
    const float* bn1v = (const float*)d_in[7];
    const float* w2   = (const float*)d_in[8];
    const float* c2b  = (const float*)d_in[9];
    const float* bn2g = (const float*)d_in[10];
    const float* bn2b = (const float*)d_in[11];
    const float* bn2m = (const float*)d_in[12];
    const float* bn2v = (const float*)d_in[13];
    const float* c3w  = (const float*)d_in[14];
    const float* c3b  = (const float*)d_in[15];
    const float* c4w  = (const float*)d_in[16];
    const float* c4b  = (const float*)d_in[17];
    const float* bn3g = (const float*)d_in[18];
    const float* bn3b = (const float*)d_in[19];
    const float* bn3m = (const float*)d_in[20];
    const float* bn3v = (const float*)d_in[21];
    const float* linw = (const float*)d_in[22];
    const float* linb = (const float*)d_in[23];

    eegnet_fused<<<dim3(16, NBL), 256, 0, stream>>>(
        eeg, c1w, c1b, bn1g, bn1b, bn1m, bn1v, w2, c2b,
        bn2g, bn2b, bn2m, bn2v, c3w, c3b, c4w, c4b,
        bn3g, bn3b, bn3m, bn3v, linw, linb, (float*)d_out);
}